// Round 8
// baseline (327.599 us; speedup 1.0000x reference)
//
#include <hip/hip_runtime.h>
#include <math.h>

typedef __bf16 bf16x8 __attribute__((ext_vector_type(8)));
typedef float f32x4 __attribute__((ext_vector_type(4)));
typedef _Float16 h2 __attribute__((ext_vector_type(2)));

__device__ __forceinline__ unsigned short f2bf(float f) {
  unsigned int u = __builtin_bit_cast(unsigned int, f);
  u += 0x7fffu + ((u >> 16) & 1u);
  return (unsigned short)(u >> 16);
}
__device__ __forceinline__ unsigned int pack2bf(float a, float b) {
  return (unsigned int)f2bf(a) | ((unsigned int)f2bf(b) << 16);
}

// ---------- bf16 MFMA GEMM + sigmoid + avgpool2 (fp32->bf16 staged inline) ----------
#define GK_PADK 40
template <int WFP32, int XFP32>
__global__ __launch_bounds__(256) void gemm_mfma_sig_pool(
    const void* __restrict__ Wv, const float* __restrict__ bias,
    const void* __restrict__ Xv, void* __restrict__ Y,
    int K, int Np, int out_bf16) {
  __shared__ unsigned short Wt[64][GK_PADK];
  __shared__ unsigned short Xt[64][GK_PADK];
  const int tid = threadIdx.x;
  const int i_base = blockIdx.x * 64;
  const int b_base = blockIdx.y * 64;
  const int srow = tid >> 2, sseg = tid & 3;
  const int wv = tid >> 6, lane = tid & 63;
  const int wn = wv & 1, wb = wv >> 1;
  const int L15 = lane & 15, q = lane >> 4;

  f32x4 acc[2][2] = {};
  for (int k0 = 0; k0 < K; k0 += 32) {
    if (WFP32) {
      const float* Wf = (const float*)Wv;
      const float4 a = *(const float4*)&Wf[(size_t)(i_base + srow) * K + k0 + sseg * 8];
      const float4 b = *(const float4*)&Wf[(size_t)(i_base + srow) * K + k0 + sseg * 8 + 4];
      uint4 p = { pack2bf(a.x, a.y), pack2bf(a.z, a.w), pack2bf(b.x, b.y), pack2bf(b.z, b.w) };
      *(uint4*)&Wt[srow][sseg * 8] = p;
    } else {
      *(uint4*)&Wt[srow][sseg * 8] =
          *(const uint4*)&((const unsigned short*)Wv)[(size_t)(i_base + srow) * K + k0 + sseg * 8];
    }
    if (XFP32) {
      const float* Xf = (const float*)Xv;
      const float4 a = *(const float4*)&Xf[(size_t)(b_base + srow) * K + k0 + sseg * 8];
      const float4 b = *(const float4*)&Xf[(size_t)(b_base + srow) * K + k0 + sseg * 8 + 4];
      uint4 p = { pack2bf(a.x, a.y), pack2bf(a.z, a.w), pack2bf(b.x, b.y), pack2bf(b.z, b.w) };
      *(uint4*)&Xt[srow][sseg * 8] = p;
    } else {
      *(uint4*)&Xt[srow][sseg * 8] =
          *(const uint4*)&((const unsigned short*)Xv)[(size_t)(b_base + srow) * K + k0 + sseg * 8];
    }
    __syncthreads();
    bf16x8 a0 = *(const bf16x8*)&Wt[wn * 32 + L15][q * 8];
    bf16x8 a1 = *(const bf16x8*)&Wt[wn * 32 + 16 + L15][q * 8];
    bf16x8 b0 = *(const bf16x8*)&Xt[wb * 32 + L15][q * 8];
    bf16x8 b1 = *(const bf16x8*)&Xt[wb * 32 + 16 + L15][q * 8];
    acc[0][0] = __builtin_amdgcn_mfma_f32_16x16x32_bf16(a0, b0, acc[0][0], 0, 0, 0);
    acc[0][1] = __builtin_amdgcn_mfma_f32_16x16x32_bf16(a0, b1, acc[0][1], 0, 0, 0);
    acc[1][0] = __builtin_amdgcn_mfma_f32_16x16x32_bf16(a1, b0, acc[1][0], 0, 0, 0);
    acc[1][1] = __builtin_amdgcn_mfma_f32_16x16x32_bf16(a1, b1, acc[1][1], 0, 0, 0);
    __syncthreads();
  }

  const int nb0 = i_base + wn * 32;
  const int bc0 = b_base + wb * 32 + L15;
#pragma unroll
  for (int mg = 0; mg < 2; mg++) {
    const int nrow = nb0 + mg * 16 + q * 4;
    const float bi0 = bias[nrow], bi1 = bias[nrow + 1];
    const float bi2 = bias[nrow + 2], bi3 = bias[nrow + 3];
#pragma unroll
    for (int bg = 0; bg < 2; bg++) {
      const int b = bc0 + bg * 16;
      f32x4 A = acc[mg][bg];
      const float a0 = __builtin_amdgcn_rcpf(1.f + __expf(-(A[0] + bi0)));
      const float a1 = __builtin_amdgcn_rcpf(1.f + __expf(-(A[1] + bi1)));
      const float a2 = __builtin_amdgcn_rcpf(1.f + __expf(-(A[2] + bi2)));
      const float a3 = __builtin_amdgcn_rcpf(1.f + __expf(-(A[3] + bi3)));
      const float p0 = 0.5f * (a0 + a1), p1 = 0.5f * (a2 + a3);
      const int pidx = nrow >> 1;  // even
      if (out_bf16) {
        *(unsigned int*)&((unsigned short*)Y)[(size_t)b * Np + pidx] = pack2bf(p0, p1);
      } else {
        *(float2*)&((float*)Y)[(size_t)b * Np + pidx] = make_float2(p0, p1);
      }
    }
  }
}

// ---------- LSTM tail ----------
// L1-BW floor analysis (R5-R7: ~1450-1520 cyc/step == 160 KB fp32 weights /
// ~128 B/cyc L1): weights now fp16-packed (80 KB/step) and per-lane live set
// shrunk to ~45 regs (2 gate rows x 13 half2) so RA's 64-reg budget fits.
// Lane (r=t>>3, gp=(t>>2)&1, kq=t&3): gp=0 -> rows {i,f}, gp=1 -> {g,o};
// k-pairs p = kq+4m (m=0..12). h stored as fp16 pairs in LDS (conflict-free
// b32 broadcasts). Dots via v_dot2_f32_f16 (fp32 accumulate). Quad butterfly
// (kq) + ds_swizzle xor-4 (gp exchange) -> every lane has all 4 gate sums ->
// replicated activations/c/h, ONE barrier per step.
#define HID 100
#define TSTEPS 256
#define LTHREADS 832

#if __has_builtin(__builtin_amdgcn_fdot2)
#define FDOT(a, b, c) __builtin_amdgcn_fdot2((a), (b), (c), false)
#else
__device__ __forceinline__ float FDOT(h2 a, h2 b, float c) {
  c = fmaf((float)a.x, (float)b.x, c);
  c = fmaf((float)a.y, (float)b.y, c);
  return c;
}
#endif

__device__ __forceinline__ float qx1(float x) {
  int v = __builtin_amdgcn_mov_dpp(__builtin_bit_cast(int, x), 0xB1, 0xf, 0xf, true);
  return x + __builtin_bit_cast(float, v);
}
__device__ __forceinline__ float qx2(float x) {
  int v = __builtin_amdgcn_mov_dpp(__builtin_bit_cast(int, x), 0x4E, 0xf, 0xf, true);
  return x + __builtin_bit_cast(float, v);
}
__device__ __forceinline__ float swz4(float x) {  // lane ^= 4 (gp exchange)
  int v = __builtin_amdgcn_ds_swizzle(__builtin_bit_cast(int, x), 0x101F);
  return __builtin_bit_cast(float, v);
}

__global__ __launch_bounds__(LTHREADS) void lstm_tail(
    const float* __restrict__ X, const float* __restrict__ Wih,
    const float* __restrict__ Whh, const float* __restrict__ bgates,
    const float* __restrict__ Wout, const float* __restrict__ bout,
    float* __restrict__ out) {
  const int bat = blockIdx.x;
  const int t = threadIdx.x;
  const int r = t >> 3;          // hidden row 0..103 (valid < 100)
  const int gp = (t >> 2) & 1;   // 0 -> (i,f), 1 -> (g,o)
  const int kq = t & 3;          // k-pair class (p mod 4)
  const bool valid = (r < HID);
  const int rr = valid ? r : 0;
  const int rowA = gp * 200 + rr;   // i or g
  const int rowB = rowA + 100;      // f or o

  __shared__ __align__(16) h2 hbuf[2][64];   // fp16 h pairs (50 used, zero-pad)
  __shared__ float xrow[TSTEPS];
  __shared__ float red[HID];

  for (int i = t; i < TSTEPS; i += LTHREADS) xrow[i] = X[(size_t)bat * TSTEPS + i];
  if (t < 64) { hbuf[0][t] = (h2){(_Float16)0.f, (_Float16)0.f};
                hbuf[1][t] = (h2){(_Float16)0.f, (_Float16)0.f}; }

  // ---- load + convert weights: 13 named half2 per gate row (no arrays) ----
#define DECLW(P) h2 P##_0, P##_1, P##_2, P##_3, P##_4, P##_5, P##_6, \
                    P##_7, P##_8, P##_9, P##_10, P##_11, P##_12;
  DECLW(wa) DECLW(wb)
#undef DECLW
#define LOADP(m)                                                              \
  { const int p = kq + 4 * (m);                                               \
    float fx = 0.f, fy = 0.f, gx = 0.f, gy = 0.f;                             \
    if (p <= 49) {                                                            \
      const float2 va = *(const float2*)&Whh[(size_t)rowA * HID + 2 * p];     \
      const float2 vb = *(const float2*)&Whh[(size_t)rowB * HID + 2 * p];     \
      fx = va.x; fy = va.y; gx = vb.x; gy = vb.y;                             \
    }                                                                         \
    wa_##m = (h2){(_Float16)fx, (_Float16)fy};                                \
    wb_##m = (h2){(_Float16)gx, (_Float16)gy}; }
  LOADP(0) LOADP(1) LOADP(2) LOADP(3) LOADP(4) LOADP(5) LOADP(6)
  LOADP(7) LOADP(8) LOADP(9) LOADP(10) LOADP(11) LOADP(12)
#undef LOADP

  const float bA = bgates[rowA], bB = bgates[rowB];
  const float uA = Wih[rowA],    uB = Wih[rowB];
  float c = 0.f;
  __syncthreads();

  for (int step = 0; step < TSTEPS; step++) {
    const int cur = step & 1;
    const h2* hq = &hbuf[cur][0];
    float za = 0.f, zb = 0.f;
#define DOTP(m)                                   \
    { const h2 hp = hq[kq + 4 * (m)];             \
      za = FDOT(wa_##m, hp, za);                  \
      zb = FDOT(wb_##m, hp, zb); }
    DOTP(0) DOTP(1) DOTP(2) DOTP(3) DOTP(4) DOTP(5) DOTP(6)
    DOTP(7) DOTP(8) DOTP(9) DOTP(10) DOTP(11) DOTP(12)
#undef DOTP
    // quad butterfly over kq -> full 100-k sums in every quad lane
    za = qx2(qx1(za));
    zb = qx2(qx1(zb));
    const float xt = xrow[step];
    za += fmaf(uA, xt, bA);
    zb += fmaf(uB, xt, bB);
    // exchange across gp (lane^4): other pair's full sums
    const float oza = swz4(za), ozb = swz4(zb);
    const float zi = gp ? oza : za;
    const float zf = gp ? ozb : zb;
    const float zg = gp ? za : oza;
    const float zo = gp ? zb : ozb;
    const float ai = __builtin_amdgcn_rcpf(1.f + __expf(-zi));
    const float af = __builtin_amdgcn_rcpf(1.f + __expf(-zf));
    const float ag = 2.f * __builtin_amdgcn_rcpf(1.f + __expf(-2.f * zg)) - 1.f;
    const float ao = __builtin_amdgcn_rcpf(1.f + __expf(-zo));
    c = fmaf(af, c, ai * ag);
    const float th = 2.f * __builtin_amdgcn_rcpf(1.f + __expf(-2.f * c)) - 1.f;
    const float h = ao * th;
    if (((t & 7) == 0) && valid) {
      ((_Float16*)&hbuf[cur ^ 1][0])[r] = (_Float16)h;
    }
    __syncthreads();
  }

  // final h in hbuf[0] (256 steps, even): out[bat] = dot(h, Wout) + bout
  if (t < HID) red[t] = (float)((const _Float16*)&hbuf[0][0])[t] * Wout[t];
  __syncthreads();
  if (t == 0) {
    float s = 0.f;
#pragma unroll
    for (int k = 0; k < HID; k++) s += red[k];
    out[bat] = s + bout[0];
  }
}

// ---------- launch ----------
extern "C" void kernel_launch(void* const* d_in, const int* in_sizes, int n_in,
                              void* d_out, int out_size, void* d_ws, size_t ws_size,
                              hipStream_t stream) {
  const float* x    = (const float*)d_in[0];   // (256,1024)
  const float* W1L  = (const float*)d_in[3];   // (1024,1024)
  const float* b1L  = (const float*)d_in[4];
  const float* W2L  = (const float*)d_in[7];   // (512,512)
  const float* b2L  = (const float*)d_in[8];
  const float* Wih3 = (const float*)d_in[15];  // (400,1)
  const float* Whh3 = (const float*)d_in[16];  // (400,100)
  const float* b3   = (const float*)d_in[17];  // (400,)
  const float* Wout = (const float*)d_in[18];  // (1,100)
  const float* bout = (const float*)d_in[19];  // (1,)
  float* out = (float*)d_out;                  // (256,)

  unsigned short* xl1b = (unsigned short*)d_ws;     // 256x512 bf16
  float* xl2 = (float*)(xl1b + (size_t)256 * 512);  // 256x256 f32

  gemm_mfma_sig_pool<1, 1><<<dim3(16, 4), 256, 0, stream>>>(W1L, b1L, x, xl1b, 1024, 512, 1);
  gemm_mfma_sig_pool<1, 0><<<dim3(8, 4), 256, 0, stream>>>(W2L, b2L, xl1b, xl2, 512, 256, 0);
  lstm_tail<<<256, LTHREADS, 0, stream>>>(xl2, Wih3, Whh3, b3, Wout, bout, out);
}

// Round 9
// 277.778 us; speedup vs baseline: 1.1794x; 1.1794x over previous
//
#include <hip/hip_runtime.h>
#include <math.h>

typedef __bf16 bf16x8 __attribute__((ext_vector_type(8)));
typedef float f32x4 __attribute__((ext_vector_type(4)));

__device__ __forceinline__ unsigned short f2bf(float f) {
  unsigned int u = __builtin_bit_cast(unsigned int, f);
  u += 0x7fffu + ((u >> 16) & 1u);
  return (unsigned short)(u >> 16);
}
__device__ __forceinline__ unsigned int pack2bf(float a, float b) {
  return (unsigned int)f2bf(a) | ((unsigned int)f2bf(b) << 16);
}

// ---------- bf16 MFMA GEMM + sigmoid + avgpool2 (fp32->bf16 staged inline) ----------
#define GK_PADK 40
template <int WFP32, int XFP32>
__global__ __launch_bounds__(256) void gemm_mfma_sig_pool(
    const void* __restrict__ Wv, const float* __restrict__ bias,
    const void* __restrict__ Xv, void* __restrict__ Y,
    int K, int Np, int out_bf16) {
  __shared__ unsigned short Wt[64][GK_PADK];
  __shared__ unsigned short Xt[64][GK_PADK];
  const int tid = threadIdx.x;
  const int i_base = blockIdx.x * 64;
  const int b_base = blockIdx.y * 64;
  const int srow = tid >> 2, sseg = tid & 3;
  const int wv = tid >> 6, lane = tid & 63;
  const int wn = wv & 1, wb = wv >> 1;
  const int L15 = lane & 15, q = lane >> 4;

  f32x4 acc[2][2] = {};
  for (int k0 = 0; k0 < K; k0 += 32) {
    if (WFP32) {
      const float* Wf = (const float*)Wv;
      const float4 a = *(const float4*)&Wf[(size_t)(i_base + srow) * K + k0 + sseg * 8];
      const float4 b = *(const float4*)&Wf[(size_t)(i_base + srow) * K + k0 + sseg * 8 + 4];
      uint4 p = { pack2bf(a.x, a.y), pack2bf(a.z, a.w), pack2bf(b.x, b.y), pack2bf(b.z, b.w) };
      *(uint4*)&Wt[srow][sseg * 8] = p;
    } else {
      *(uint4*)&Wt[srow][sseg * 8] =
          *(const uint4*)&((const unsigned short*)Wv)[(size_t)(i_base + srow) * K + k0 + sseg * 8];
    }
    if (XFP32) {
      const float* Xf = (const float*)Xv;
      const float4 a = *(const float4*)&Xf[(size_t)(b_base + srow) * K + k0 + sseg * 8];
      const float4 b = *(const float4*)&Xf[(size_t)(b_base + srow) * K + k0 + sseg * 8 + 4];
      uint4 p = { pack2bf(a.x, a.y), pack2bf(a.z, a.w), pack2bf(b.x, b.y), pack2bf(b.z, b.w) };
      *(uint4*)&Xt[srow][sseg * 8] = p;
    } else {
      *(uint4*)&Xt[srow][sseg * 8] =
          *(const uint4*)&((const unsigned short*)Xv)[(size_t)(b_base + srow) * K + k0 + sseg * 8];
    }
    __syncthreads();
    bf16x8 a0 = *(const bf16x8*)&Wt[wn * 32 + L15][q * 8];
    bf16x8 a1 = *(const bf16x8*)&Wt[wn * 32 + 16 + L15][q * 8];
    bf16x8 b0 = *(const bf16x8*)&Xt[wb * 32 + L15][q * 8];
    bf16x8 b1 = *(const bf16x8*)&Xt[wb * 32 + 16 + L15][q * 8];
    acc[0][0] = __builtin_amdgcn_mfma_f32_16x16x32_bf16(a0, b0, acc[0][0], 0, 0, 0);
    acc[0][1] = __builtin_amdgcn_mfma_f32_16x16x32_bf16(a0, b1, acc[0][1], 0, 0, 0);
    acc[1][0] = __builtin_amdgcn_mfma_f32_16x16x32_bf16(a1, b0, acc[1][0], 0, 0, 0);
    acc[1][1] = __builtin_amdgcn_mfma_f32_16x16x32_bf16(a1, b1, acc[1][1], 0, 0, 0);
    __syncthreads();
  }

  const int nb0 = i_base + wn * 32;
  const int bc0 = b_base + wb * 32 + L15;
#pragma unroll
  for (int mg = 0; mg < 2; mg++) {
    const int nrow = nb0 + mg * 16 + q * 4;
    const float bi0 = bias[nrow], bi1 = bias[nrow + 1];
    const float bi2 = bias[nrow + 2], bi3 = bias[nrow + 3];
#pragma unroll
    for (int bg = 0; bg < 2; bg++) {
      const int b = bc0 + bg * 16;
      f32x4 A = acc[mg][bg];
      const float a0 = __builtin_amdgcn_rcpf(1.f + __expf(-(A[0] + bi0)));
      const float a1 = __builtin_amdgcn_rcpf(1.f + __expf(-(A[1] + bi1)));
      const float a2 = __builtin_amdgcn_rcpf(1.f + __expf(-(A[2] + bi2)));
      const float a3 = __builtin_amdgcn_rcpf(1.f + __expf(-(A[3] + bi3)));
      const float p0 = 0.5f * (a0 + a1), p1 = 0.5f * (a2 + a3);
      const int pidx = nrow >> 1;  // even
      if (out_bf16) {
        *(unsigned int*)&((unsigned short*)Y)[(size_t)b * Np + pidx] = pack2bf(p0, p1);
      } else {
        *(float2*)&((float*)Y)[(size_t)b * Np + pidx] = make_float2(p0, p1);
      }
    }
  }
}

// ---------- LSTM tail ----------
// Lane (r=t>>2, kq=t&3) owns all 4 gates of hidden row r over k-quarter
// [25kq, 25kq+25) -> 100 fp32 weights/lane. Residency enforcement: ONE asm
// statement with all 28 "+v" operands (100 floats) per iteration. R7's
// mistake was 4 separate asm statements -> RA kept only one gate's weights
// resident at a time and scratch-cycled the rest (VGPR=64, no speedup).
// A single asm forces all 100 values simultaneously live in distinct VGPRs
// every step; spilling around it would cost ~200 scratch ops/iter, so RA
// must allocate (~130 regs, budget 256 via waves_per_eu(1,2), 7 waves ->
// 1 WG/CU). h in LDS at stride 36 (conflict-free, validated R6: 1.38e7 ->
// ~0 conflicts). Quad butterfly (DPP 0xB1+0x4E) completes the 100-dots;
// activations + c/h replicated per quad; one barrier per step.
#define HID 100
#define TSTEPS 256
#define HSTRIDE 36

__device__ __forceinline__ float qx1(float x) {
  int v = __builtin_amdgcn_mov_dpp(__builtin_bit_cast(int, x), 0xB1, 0xf, 0xf, true);
  return x + __builtin_bit_cast(float, v);
}
__device__ __forceinline__ float qx2(float x) {
  int v = __builtin_amdgcn_mov_dpp(__builtin_bit_cast(int, x), 0x4E, 0xf, 0xf, true);
  return x + __builtin_bit_cast(float, v);
}

__global__ __launch_bounds__(448) __attribute__((amdgpu_waves_per_eu(1, 2)))
void lstm_tail(
    const float* __restrict__ X, const float* __restrict__ Wih,
    const float* __restrict__ Whh, const float* __restrict__ bgates,
    const float* __restrict__ Wout, const float* __restrict__ bout,
    float* __restrict__ out) {
  const int bat = blockIdx.x;
  const int t = threadIdx.x;
  const int r = t >> 2;        // hidden row (valid < 100)
  const int kq = t & 3;        // k quarter
  const int koff = 25 * kq;
  const bool valid = (r < HID);
  const int rr = valid ? r : 0;
  __shared__ __align__(16) float hbuf[2][160];
  __shared__ float xrow[TSTEPS];
  __shared__ float red[HID];

  for (int i = t; i < TSTEPS; i += 448) xrow[i] = X[(size_t)bat * TSTEPS + i];

  const float* Wr0 = &Whh[(size_t)(0 * HID + rr) * HID + koff];
  const float* Wr1 = &Whh[(size_t)(1 * HID + rr) * HID + koff];
  const float* Wr2 = &Whh[(size_t)(2 * HID + rr) * HID + koff];
  const float* Wr3 = &Whh[(size_t)(3 * HID + rr) * HID + koff];

#define DECLW(P) f32x4 P##_0, P##_1, P##_2, P##_3, P##_4, P##_5; float P##_6;
  DECLW(wi) DECLW(wf) DECLW(wg) DECLW(wo)
#undef DECLW
#define LW(P, B)                                               \
  P##_0 = (f32x4){B[0],  B[1],  B[2],  B[3]};                  \
  P##_1 = (f32x4){B[4],  B[5],  B[6],  B[7]};                  \
  P##_2 = (f32x4){B[8],  B[9],  B[10], B[11]};                 \
  P##_3 = (f32x4){B[12], B[13], B[14], B[15]};                 \
  P##_4 = (f32x4){B[16], B[17], B[18], B[19]};                 \
  P##_5 = (f32x4){B[20], B[21], B[22], B[23]};                 \
  P##_6 = B[24];
  LW(wi, Wr0) LW(wf, Wr1) LW(wg, Wr2) LW(wo, Wr3)
#undef LW

  const float bi_ = bgates[0 * HID + rr], bf_ = bgates[1 * HID + rr];
  const float bg_ = bgates[2 * HID + rr], bo_ = bgates[3 * HID + rr];
  const float ui = Wih[0 * HID + rr], uf = Wih[1 * HID + rr];
  const float ug = Wih[2 * HID + rr], uo = Wih[3 * HID + rr];

  const int hpos = (rr / 25) * HSTRIDE + (rr % 25);  // conflict-free chunk slot

  if (t < 160) { hbuf[0][t] = 0.f; hbuf[1][t] = 0.f; }
  float c = 0.f;
  __syncthreads();

  for (int step = 0; step < TSTEPS; step++) {
    // SINGLE opaque touch of ALL 100 weight floats: forces simultaneous VGPR
    // residency each iteration (28 operands, under the 30-operand asm limit).
    asm volatile(""
        : "+v"(wi_0), "+v"(wi_1), "+v"(wi_2), "+v"(wi_3), "+v"(wi_4), "+v"(wi_5), "+v"(wi_6),
          "+v"(wf_0), "+v"(wf_1), "+v"(wf_2), "+v"(wf_3), "+v"(wf_4), "+v"(wf_5), "+v"(wf_6),
          "+v"(wg_0), "+v"(wg_1), "+v"(wg_2), "+v"(wg_3), "+v"(wg_4), "+v"(wg_5), "+v"(wg_6),
          "+v"(wo_0), "+v"(wo_1), "+v"(wo_2), "+v"(wo_3), "+v"(wo_4), "+v"(wo_5), "+v"(wo_6));
    const float* hq = &hbuf[step & 1][kq * HSTRIDE];
    float z0 = 0.f, z1 = 0.f, z2 = 0.f, z3 = 0.f;
#define G4(OFF, WI, WF, WG, WO)                                                  \
    { const float4 h4 = *(const float4*)&hq[OFF];                                \
      z0 = fmaf(WI[0], h4.x, z0); z1 = fmaf(WF[0], h4.x, z1);                    \
      z2 = fmaf(WG[0], h4.x, z2); z3 = fmaf(WO[0], h4.x, z3);                    \
      z0 = fmaf(WI[1], h4.y, z0); z1 = fmaf(WF[1], h4.y, z1);                    \
      z2 = fmaf(WG[1], h4.y, z2); z3 = fmaf(WO[1], h4.y, z3);                    \
      z0 = fmaf(WI[2], h4.z, z0); z1 = fmaf(WF[2], h4.z, z1);                    \
      z2 = fmaf(WG[2], h4.z, z2); z3 = fmaf(WO[2], h4.z, z3);                    \
      z0 = fmaf(WI[3], h4.w, z0); z1 = fmaf(WF[3], h4.w, z1);                    \
      z2 = fmaf(WG[3], h4.w, z2); z3 = fmaf(WO[3], h4.w, z3); }
    G4(0,  wi_0, wf_0, wg_0, wo_0)
    G4(4,  wi_1, wf_1, wg_1, wo_1)
    G4(8,  wi_2, wf_2, wg_2, wo_2)
    G4(12, wi_3, wf_3, wg_3, wo_3)
    G4(16, wi_4, wf_4, wg_4, wo_4)
    G4(20, wi_5, wf_5, wg_5, wo_5)
    { const float h1 = hq[24];
      z0 = fmaf(wi_6, h1, z0); z1 = fmaf(wf_6, h1, z1);
      z2 = fmaf(wg_6, h1, z2); z3 = fmaf(wo_6, h1, z3); }
#undef G4
    // quad butterfly: every lane of the quad gets the full 100-k sums
    z0 = qx2(qx1(z0)); z1 = qx2(qx1(z1)); z2 = qx2(qx1(z2)); z3 = qx2(qx1(z3));

    const float xt = xrow[step];
    const float zi = fmaf(ui, xt, z0 + bi_);
    const float zf = fmaf(uf, xt, z1 + bf_);
    const float zg = fmaf(ug, xt, z2 + bg_);
    const float zo = fmaf(uo, xt, z3 + bo_);
    const float ai = __builtin_amdgcn_rcpf(1.f + __expf(-zi));
    const float af = __builtin_amdgcn_rcpf(1.f + __expf(-zf));
    const float ag = 2.f * __builtin_amdgcn_rcpf(1.f + __expf(-2.f * zg)) - 1.f;
    const float ao = __builtin_amdgcn_rcpf(1.f + __expf(-zo));
    c = fmaf(af, c, ai * ag);
    const float th = 2.f * __builtin_amdgcn_rcpf(1.f + __expf(-2.f * c)) - 1.f;
    if (kq == 0 && valid) hbuf[(step & 1) ^ 1][hpos] = ao * th;
    __syncthreads();
  }

  if (t < HID) red[t] = hbuf[0][(t / 25) * HSTRIDE + (t % 25)] * Wout[t];
  __syncthreads();
  if (t == 0) {
    float s = 0.f;
#pragma unroll
    for (int k = 0; k < HID; k++) s += red[k];
    out[bat] = s + bout[0];
  }
}

// ---------- launch ----------
extern "C" void kernel_launch(void* const* d_in, const int* in_sizes, int n_in,
                              void* d_out, int out_size, void* d_ws, size_t ws_size,
                              hipStream_t stream) {
  const float* x    = (const float*)d_in[0];   // (256,1024)
  const float* W1L  = (const float*)d_in[3];   // (1024,1024)
  const float* b1L  = (const float*)d_in[4];
  const float* W2L  = (const float*)d_in[7];   // (512,512)
  const float* b2L  = (const float*)d_in[8];
  const float* Wih3 = (const float*)d_in[15];  // (400,1)
  const float* Whh3 = (const float*)d_in[16];  // (400,100)
  const float* b3   = (const float*)d_in[17];  // (400,)
  const float* Wout = (const float*)d_in[18];  // (1,100)
  const float* bout = (const float*)d_in[19];  // (1,)
  float* out = (float*)d_out;                  // (256,)

  unsigned short* xl1b = (unsigned short*)d_ws;     // 256x512 bf16
  float* xl2 = (float*)(xl1b + (size_t)256 * 512);  // 256x256 f32

  gemm_mfma_sig_pool<1, 1><<<dim3(16, 4), 256, 0, stream>>>(W1L, b1L, x, xl1b, 1024, 512, 1);
  gemm_mfma_sig_pool<1, 0><<<dim3(8, 4), 256, 0, stream>>>(W2L, b2L, xl1b, xl2, 512, 256, 0);
  lstm_tail<<<256, 448, 0, stream>>>(xl2, Wih3, Whh3, b3, Wout, bout, out);
}